// Round 1
// baseline (11785.246 us; speedup 1.0000x reference)
//
#include <hip/hip_runtime.h>

#define TT 32   // tags
#define LL 16   // max span length
#define PD 7    // prefetch depth (steps ahead); 8*PD=56 loads in flight < 63

// ---------------------------------------------------------------------------
// Kernel 1: EF = exp(w2 * feats), elementwise (vectorized float4)
// ---------------------------------------------------------------------------
__global__ void ef_exp_kernel(const float* __restrict__ feats,
                              const float* __restrict__ w2p,
                              float* __restrict__ ef, int n4) {
    const float w2 = w2p[0];
    int idx = blockIdx.x * blockDim.x + threadIdx.x;
    int stride = gridDim.x * blockDim.x;
    const float4* f4 = (const float4*)feats;
    float4* e4 = (float4*)ef;
    for (int i = idx; i < n4; i += stride) {
        float4 v = f4[i];
        float4 r;
        r.x = __expf(w2 * v.x);
        r.y = __expf(w2 * v.y);
        r.z = __expf(w2 * v.z);
        r.w = __expf(w2 * v.w);
        e4[i] = r;
    }
}

// ---------------------------------------------------------------------------
// Kernel 2: single-wave sequential semi-CRF scan.
//
// State per step s: 16 "rows" (slots), row q holds the forward variable of
// step s' (s' = latest step < s with s' == q mod 16) as:
//   D[q][t]  = sum_p exp(w1*trans[t][p]) * exp(fv_{s'}[p] - M[q])   (persistent!)
//   rs[q]    = exp(M[q] - mref)                                      (scale)
// Step: S_t = sum_q D[q][t] * EF[l][s-l][t] * rs[q]   (l = s-1-s')
//       fv_s[t] = mref + log(S_t);  new row: Hnorm = S/maxS, rs = maxS,
//       D_new[t] = (sum_p Trx[t][p]*S_p)/maxS  -- no exp/log on the chain.
// Lane layout: t = lane&31, h = lane>>5; lane owns slots 8h..8h+7.
// ---------------------------------------------------------------------------
template<bool USE_EF>
__launch_bounds__(64, 1)
__global__ void semicrf_scan_kernel(const float* __restrict__ src,   // EF or feats
                                    const float* __restrict__ trans,
                                    const float* __restrict__ tbound,
                                    const float* __restrict__ w1p,
                                    const float* __restrict__ w2p,
                                    float* __restrict__ out, int S) {
    __shared__ float ldsS[TT];
    const int lane = threadIdx.x;
    const int t = lane & 31;
    const int h = lane >> 5;
    const float w1 = w1p[0];
    const float w2 = w2p[0];
    const size_t planeE = (size_t)S * TT;       // one l-plane, in elements
    const float* basePtr = src + t;

    // Trx[t][p] for p in lane's half, register-resident forever.
    float trx[16];
#pragma unroll
    for (int i = 0; i < 16; ++i)
        trx[i] = __expf(w1 * trans[t * TT + h * 16 + i]);

    float D[8], rs[8];
#pragma unroll
    for (int k = 0; k < 8; ++k) { D[k] = 0.0f; rs[k] = 0.0f; }

    // prefetch ring: ring[st & 7][k] holds EF value for target step st, slot 8h+k
    float ring[8][8];
    const float* ptr[8];

    // prologue: fill pipeline for target steps 0..PD-1
#pragma unroll
    for (int st = 0; st < PD; ++st) {
#pragma unroll
        for (int k = 0; k < 8; ++k) {
            int q = h * 8 + k;
            int l = (st - 1 - q) & 15;          // span-length index at step st
            int c = st - l; if (c < 0) c = 0;   // column (clamped; masked rows)
            ptr[k] = basePtr + ((size_t)l * S + (size_t)c) * TT;
            ring[st & 7][k] = ptr[k][0];
        }
    }

    // block-0 boundary emissions: bscore_t(s) = w1*tb0[t] + w2*feats[s][0][t]
    float etb0 = __expf(w1 * tbound[t]);
    float bem[16];
#pragma unroll
    for (int j = 0; j < 16; ++j) {
        float v = src[(size_t)j * planeE + (size_t)t];
        bem[j] = USE_EF ? v : __expf(w2 * v);
    }

    float mref = 0.0f;       // running log-shift (updated once per 16 steps)
    float Sfinal = 1.0f;     // S_t of the final step (for the terminal LSE)

#define SCRF_STEP(J, S0, IS_B0)                                               \
    {                                                                         \
        const int j_ = (J);                                                   \
        /* ---- prefetch pointer advance/reset for target st = S0+j_+PD --- */\
        const int qn = (j_ + PD - 1) & 15;  /* slot replaced before target */ \
        const int kn = qn & 7;                                                \
        const int hn = qn >> 3;                                               \
        {                                                                     \
            long st_ = (long)(S0) + j_ + PD;                                  \
            long c_ = st_ <= (long)(S - 1) ? st_ : (long)(S - 1);             \
            const float* rp_ = basePtr + (size_t)c_ * TT;  /* l=0 plane */    \
            _Pragma("unroll")                                                 \
            for (int k = 0; k < 8; ++k) {                                     \
                if (k == kn) ptr[k] = (h == hn) ? rp_ : (ptr[k] + planeE);    \
                else         ptr[k] += planeE;                                \
            }                                                                 \
        }                                                                     \
        _Pragma("unroll")                                                     \
        for (int k = 0; k < 8; ++k) ring[(j_ + PD) & 7][k] = ptr[k][0];       \
        /* ---- Ew = EF * rs (rs==0 masks not-yet-existing rows) ---------- */\
        float ew[8];                                                          \
        _Pragma("unroll")                                                     \
        for (int k = 0; k < 8; ++k) {                                         \
            float v_ = ring[j_ & 7][k];                                       \
            if (!USE_EF) v_ = __expf(w2 * v_);                                \
            ew[k] = v_ * rs[k];                                               \
        }                                                                     \
        /* ---- S_t = sum_q D*Ew (half), then combine halves --------------- */\
        float p0 = 0.0f, p1 = 0.0f;                                           \
        _Pragma("unroll")                                                     \
        for (int k = 0; k < 8; k += 2) {                                      \
            p0 = fmaf(D[k], ew[k], p0);                                       \
            p1 = fmaf(D[k + 1], ew[k + 1], p1);                               \
        }                                                                     \
        float partial = p0 + p1;                                              \
        { /* O-tag (t==0) allows only span length 1 => only slot (s-1)&15 */  \
            const int rp2 = (j_ - 1) & 15;                                    \
            const int kp = rp2 & 7;                                           \
            const int hp = rp2 >> 3;                                          \
            float alt = (h == hp) ? D[kp] * ew[kp] : 0.0f;                    \
            partial = (t == 0) ? alt : partial;                               \
        }                                                                     \
        float Sv = partial + __shfl_xor(partial, 32);                         \
        if (IS_B0) { /* sentence-start boundary term, steps 0..15 only */     \
            float bt = etb0 * bem[j_];                                        \
            if (j_ > 0) bt = (t == 0) ? 0.0f : bt;                            \
            Sv += bt;                                                         \
        }                                                                     \
        /* ---- maxS over all 32 tags (both halves hold all t) ------------- */\
        float mx = Sv;                                                        \
        _Pragma("unroll")                                                     \
        for (int m_ = 1; m_ <= 16; m_ <<= 1)                                  \
            mx = fmaxf(mx, __shfl_xor(mx, m_));                               \
        /* ---- broadcast S_p via LDS, build D_new (t <- p transpose) ------ */\
        ldsS[t] = Sv;                                                         \
        __syncthreads();                                                      \
        float dn0 = 0.0f, dn1 = 0.0f, dn2 = 0.0f, dn3 = 0.0f;                 \
        _Pragma("unroll")                                                     \
        for (int i = 0; i < 16; i += 4) {                                     \
            dn0 = fmaf(trx[i + 0], ldsS[16 * h + i + 0], dn0);                \
            dn1 = fmaf(trx[i + 1], ldsS[16 * h + i + 1], dn1);                \
            dn2 = fmaf(trx[i + 2], ldsS[16 * h + i + 2], dn2);                \
            dn3 = fmaf(trx[i + 3], ldsS[16 * h + i + 3], dn3);                \
        }                                                                     \
        float dh = (dn0 + dn1) + (dn2 + dn3);                                 \
        float dnew = dh + __shfl_xor(dh, 32);                                 \
        float Dn = dnew * (1.0f / mx);                                        \
        /* ---- insert new row at slot j_ (compile-time) ------------------- */\
        const int kr = j_ & 7;                                                \
        const int hr = j_ >> 3;                                               \
        D[kr]  = (h == hr) ? Dn : D[kr];                                      \
        rs[kr] = (h == hr) ? mx : rs[kr];                                     \
        Sfinal = Sv;                                                          \
    }

    // ---- block 0 (steps 0..15, includes boundary terms; mref = 0) ----
#pragma unroll
    for (int j = 0; j < 16; ++j) {
        SCRF_STEP(j, 0, true)
    }

    // ---- generic blocks ----
    const int nblocks = S / 16;
    long s0 = 16;
    for (int b = 1; b < nblocks; ++b) {
        // re-anchor shift to the most recent row (slot 15, held by h=1 lanes)
        float rs15 = __shfl(rs[7], 32);
        mref += __logf(rs15);
        float inv = 1.0f / rs15;
#pragma unroll
        for (int k = 0; k < 8; ++k) rs[k] *= inv;
#pragma unroll
        for (int j = 0; j < 16; ++j) {
            SCRF_STEP(j, s0, false)
        }
        s0 += 16;
    }

    // ---- terminal: out = LSE_t( fv_{S-1}[t] + w1*tb1[t] )
    //              = mref + log( sum_t Sfinal_t * exp(w1*tb1[t]) )
    float etb1 = __expf(w1 * tbound[TT + t]);
    float val = Sfinal * etb1;
#pragma unroll
    for (int m = 1; m <= 16; m <<= 1) val += __shfl_xor(val, m);
    if (lane == 0) out[0] = mref + __logf(val);
#undef SCRF_STEP
}

// ---------------------------------------------------------------------------
extern "C" void kernel_launch(void* const* d_in, const int* in_sizes, int n_in,
                              void* d_out, int out_size, void* d_ws, size_t ws_size,
                              hipStream_t stream) {
    const float* feats = (const float*)d_in[0];   // [L=16, S, T=32]
    const float* trans = (const float*)d_in[1];   // [T, T]
    const float* tb    = (const float*)d_in[2];   // [2, T]
    const float* w1    = (const float*)d_in[3];
    const float* w2    = (const float*)d_in[4];
    // d_in[5] = seqlen (redundant with feats shape)
    float* out = (float*)d_out;

    const int n = in_sizes[0];            // L*S*T
    const int S = n / (LL * TT);
    const size_t need = (size_t)n * sizeof(float);

    if (ws_size >= need) {
        float* ef = (float*)d_ws;
        ef_exp_kernel<<<2048, 256, 0, stream>>>(feats, w2, ef, n / 4);
        semicrf_scan_kernel<true><<<1, 64, 0, stream>>>(ef, trans, tb, w1, w2, out, S);
    } else {
        semicrf_scan_kernel<false><<<1, 64, 0, stream>>>(feats, trans, tb, w1, w2, out, S);
    }
}

// Round 2
// 7724.093 us; speedup vs baseline: 1.5258x; 1.5258x over previous
//
#include <hip/hip_runtime.h>

#define TT 32   // tags
#define LL 16   // max span length
#define PD 4    // prefetch depth (steps ahead)
#define RD 4    // ring depth (== PD; consume-then-overwrite per step)

// ---------------------------------------------------------------------------
// Kernel 1: EF = exp(w2 * feats), elementwise (vectorized float4)
// ---------------------------------------------------------------------------
__global__ void ef_exp_kernel(const float* __restrict__ feats,
                              const float* __restrict__ w2p,
                              float* __restrict__ ef, int n4) {
    const float w2 = w2p[0];
    int idx = blockIdx.x * blockDim.x + threadIdx.x;
    int stride = gridDim.x * blockDim.x;
    const float4* f4 = (const float4*)feats;
    float4* e4 = (float4*)ef;
    for (int i = idx; i < n4; i += stride) {
        float4 v = f4[i];
        float4 r;
        r.x = __expf(w2 * v.x);
        r.y = __expf(w2 * v.y);
        r.z = __expf(w2 * v.z);
        r.w = __expf(w2 * v.w);
        e4[i] = r;
    }
}

// ---------------------------------------------------------------------------
// Kernel 2: single-wave sequential semi-CRF scan, block-amortized scaling.
//
// All 16 history rows share one scale mref (re-anchored once per 16 steps).
// Lane (t = lane&31, h = lane>>5) keeps, for ALL 16 slots q:
//   D[q] = sum_{p in half h} Trx[t][p] * exp(fv_{s'(q)}[p] - mref)
// Steady-state step s (slot j = s&15):
//   part   = sum_q D[q] * EF[l_q][s'_q+1][t]          (half-p, all slots)
//   Sv     = part + shfl_xor(part,32)                 (full S_t)
//   ldsS[t]=Sv; barrier; read S_p (4x b128); dh = sum_i trx[i]*S_p  -> D[j]=dh
// No per-step max/rcp; once per block: mx=max_t(Sv), D *= e^-20/mx,
// mref += log(mx)+20.
// ---------------------------------------------------------------------------
template<bool USE_EF>
__launch_bounds__(64, 1)
__global__ void semicrf_scan_kernel(const float* __restrict__ src,   // EF or feats
                                    const float* __restrict__ trans,
                                    const float* __restrict__ tbound,
                                    const float* __restrict__ w1p,
                                    const float* __restrict__ w2p,
                                    float* __restrict__ out, int S) {
    __shared__ float4 ldsS4[8];
    const int lane = threadIdx.x;
    const int t = lane & 31;
    const int h = lane >> 5;
    const float w1 = w1p[0];
    const float w2 = w2p[0];
    const unsigned toff = (unsigned)t * 4u;
    const unsigned planeB = (unsigned)S * 128u;       // bytes per l-plane
    const size_t planeE = (size_t)S * TT;             // elements per l-plane

    // Trx half-row, register-resident.
    float trx[16];
#pragma unroll
    for (int i = 0; i < 16; ++i)
        trx[i] = __expf(w1 * trans[t * TT + h * 16 + i]);

    float D[16];
#pragma unroll
    for (int k = 0; k < 16; ++k) D[k] = 0.0f;

    // 32-bit byte offsets (include t) against uniform base `src`.
    // Invariant at entry of step s: off[] addresses EF for target step s+PD.
    unsigned off[16];
#pragma unroll
    for (int k = 0; k < 16; ++k) {                    // target step 0
        int l = (-1 - k) & 15;
        int c = 0 - l; if (c < 0) c = 0;
        off[k] = (unsigned)(l * S + c) * 128u + toff;
    }

    float ring[RD][16];
#pragma unroll
    for (int st = 0; st < PD; ++st) {
#pragma unroll
        for (int k = 0; k < 16; ++k)
            ring[st][k] = *(const float*)((const char*)src + off[k]);
        // advance to target st+1: slot q*=st resets to (l=0, col=st+1)
        const int qr = st & 15;
        unsigned c = (unsigned)((st + 1 <= S - 1) ? st + 1 : S - 1);
#pragma unroll
        for (int k = 0; k < 16; ++k)
            off[k] = (k == qr) ? (c * 128u + toff) : (off[k] + planeB);
    }

    // sentence-start boundary terms (steps 0..15 only)
    float etb0 = __expf(w1 * tbound[t]);
    float bem[16];
#pragma unroll
    for (int j = 0; j < 16; ++j) {
        float v = src[(size_t)j * planeE + (size_t)t];
        bem[j] = USE_EF ? v : __expf(w2 * v);
    }

    float mref = 0.0f;
    float Svk = 1.0f;

#define SCRF_STEP(J, S0V, IS_B0)                                              \
    {                                                                         \
        const int j_ = (J);                                                   \
        /* ---- consume ring[j&3]: ew values for this step ----------------- */\
        float ewv[16];                                                        \
        _Pragma("unroll")                                                     \
        for (int k = 0; k < 16; ++k) {                                        \
            float v_ = ring[j_ & 3][k];                                       \
            ewv[k] = USE_EF ? v_ : __expf(w2 * v_);                           \
        }                                                                     \
        float p0 = 0.f, p1 = 0.f, p2 = 0.f, p3 = 0.f;                         \
        _Pragma("unroll")                                                     \
        for (int k = 0; k < 16; k += 4) {                                     \
            p0 = fmaf(D[k + 0], ewv[k + 0], p0);                              \
            p1 = fmaf(D[k + 1], ewv[k + 1], p1);                              \
            p2 = fmaf(D[k + 2], ewv[k + 2], p2);                              \
            p3 = fmaf(D[k + 3], ewv[k + 3], p3);                              \
        }                                                                     \
        float part = (p0 + p1) + (p2 + p3);                                   \
        { /* O-tag: only span length 1 (slot of step s-1) */                  \
            const int kp = (j_ - 1) & 15;                                     \
            float alt = D[kp] * ewv[kp];                                      \
            part = (t == 0) ? alt : part;                                     \
        }                                                                     \
        /* ---- prefetch target T=s+PD into ring[j&3]; advance offsets ----- */\
        _Pragma("unroll")                                                     \
        for (int k = 0; k < 16; ++k)                                          \
            ring[(j_ + PD) & 3][k] =                                          \
                *(const float*)((const char*)src + off[k]);                   \
        {                                                                     \
            const int qr = (j_ + PD) & 15;                                    \
            long T1 = (long)(S0V) + j_ + PD + 1;                              \
            unsigned c_ = (unsigned)(T1 <= (long)(S - 1) ? T1 : (long)(S - 1)); \
            _Pragma("unroll")                                                 \
            for (int k = 0; k < 16; ++k)                                      \
                off[k] = (k == qr) ? (c_ * 128u + toff) : (off[k] + planeB);  \
        }                                                                     \
        /* ---- full S_t, boundary, transpose via LDS ---------------------- */\
        float Sv = part + __shfl_xor(part, 32);                               \
        if (IS_B0) {                                                          \
            float bt = etb0 * bem[j_];                                        \
            if (j_ > 0) bt = (t == 0) ? 0.0f : bt;                            \
            Sv += bt;                                                         \
        }                                                                     \
        ((float*)ldsS4)[t] = Sv;                                              \
        __syncthreads();                                                      \
        float4 a0 = ldsS4[h * 4 + 0];                                         \
        float4 a1 = ldsS4[h * 4 + 1];                                         \
        float4 a2 = ldsS4[h * 4 + 2];                                         \
        float4 a3 = ldsS4[h * 4 + 3];                                         \
        float dn0 = fmaf(trx[0],  a0.x, fmaf(trx[1],  a0.y,                   \
                    fmaf(trx[2],  a0.z, trx[3]  * a0.w)));                    \
        float dn1 = fmaf(trx[4],  a1.x, fmaf(trx[5],  a1.y,                   \
                    fmaf(trx[6],  a1.z, trx[7]  * a1.w)));                    \
        float dn2 = fmaf(trx[8],  a2.x, fmaf(trx[9],  a2.y,                   \
                    fmaf(trx[10], a2.z, trx[11] * a2.w)));                    \
        float dn3 = fmaf(trx[12], a3.x, fmaf(trx[13], a3.y,                   \
                    fmaf(trx[14], a3.z, trx[15] * a3.w)));                    \
        D[j_] = (dn0 + dn1) + (dn2 + dn3);                                    \
        Svk = Sv;                                                             \
    }

    // ---- block 0 (steps 0..15, boundary terms active, mref = 0) ----
#pragma unroll
    for (int j = 0; j < 16; ++j) {
        SCRF_STEP(j, 0L, true)
    }

    // ---- main blocks ----
    const int nblocks = S / 16;
    long s0 = 16;
    for (int b = 1; b < nblocks; ++b) {
        // re-anchor: divide all rows by max_t(Sv_last), recenter to e^-20
        float mx = Svk;
#pragma unroll
        for (int m = 1; m <= 16; m <<= 1)
            mx = fmaxf(mx, __shfl_xor(mx, m));
        float inv = 2.0611536e-09f / mx;     // e^-20 / mx
        mref += __logf(mx) + 20.0f;
#pragma unroll
        for (int k = 0; k < 16; ++k) D[k] *= inv;

#pragma unroll
        for (int j = 0; j < 16; ++j) {
            SCRF_STEP(j, s0, false)
        }
        s0 += 16;
    }

    // ---- terminal: out = mref + log( sum_t Sv_last[t] * exp(w1*tb1[t]) )
    float etb1 = __expf(w1 * tbound[TT + t]);
    float val = Svk * etb1;
#pragma unroll
    for (int m = 1; m <= 16; m <<= 1) val += __shfl_xor(val, m);
    if (lane == 0) out[0] = mref + __logf(val);
#undef SCRF_STEP
}

// ---------------------------------------------------------------------------
extern "C" void kernel_launch(void* const* d_in, const int* in_sizes, int n_in,
                              void* d_out, int out_size, void* d_ws, size_t ws_size,
                              hipStream_t stream) {
    const float* feats = (const float*)d_in[0];   // [L=16, S, T=32]
    const float* trans = (const float*)d_in[1];   // [T, T]
    const float* tb    = (const float*)d_in[2];   // [2, T]
    const float* w1    = (const float*)d_in[3];
    const float* w2    = (const float*)d_in[4];
    float* out = (float*)d_out;

    const int n = in_sizes[0];            // L*S*T
    const int S = n / (LL * TT);
    const size_t need = (size_t)n * sizeof(float);

    if (ws_size >= need) {
        float* ef = (float*)d_ws;
        ef_exp_kernel<<<2048, 256, 0, stream>>>(feats, w2, ef, n / 4);
        semicrf_scan_kernel<true><<<1, 64, 0, stream>>>(ef, trans, tb, w1, w2, out, S);
    } else {
        semicrf_scan_kernel<false><<<1, 64, 0, stream>>>(feats, trans, tb, w1, w2, out, S);
    }
}

// Round 3
// 4638.216 us; speedup vs baseline: 2.5409x; 1.6653x over previous
//
#include <hip/hip_runtime.h>

#define TT 32   // tags
#define LL 16   // max span length
#define PD 7    // prefetch depth (steps ahead); 4 loads/step * 7 = 28 < 63 vmcnt cap

// ---------------------------------------------------------------------------
// lane<->lane^32 sum via permlane32_swap (VALU) with shfl fallback
// ---------------------------------------------------------------------------
__device__ __forceinline__ float swap_sum(float x) {
#if __has_builtin(__builtin_amdgcn_permlane32_swap)
    typedef unsigned int u2 __attribute__((ext_vector_type(2)));
    u2 r = __builtin_amdgcn_permlane32_swap(__float_as_uint(x), __float_as_uint(x),
                                            false, false);
    return __uint_as_float(r.x) + __uint_as_float(r.y);
#else
    return x + __shfl_xor(x, 32);
#endif
}

// ---------------------------------------------------------------------------
// Kernel 1: anti-diagonal transpose + exp.
//   EFd[st][t][l] = exp(w2 * feats[l][st-l][t])   (0 if st-l < 0)
// One block per st (512 threads). Per lane t,l: the scan's 16 emissions for a
// step become 16 CONTIGUOUS floats -> 4x dwordx4 loads in the scan.
// ---------------------------------------------------------------------------
__global__ void efd_kernel(const float* __restrict__ feats,
                           const float* __restrict__ w2p,
                           float* __restrict__ efd, int S) {
    const int st = blockIdx.x;
    const int tid = threadIdx.x;            // 0..511
    const int t = tid >> 4;
    const int l = tid & 15;
    const int c = st - l;
    const float w2 = w2p[0];
    float v = 0.0f;
    if (c >= 0) v = __expf(w2 * feats[((size_t)l * S + c) * TT + t]);
    efd[(size_t)st * 512 + tid] = v;
}

// ---------------------------------------------------------------------------
// Kernel 2: single-wave scan, NO barriers (single-wave LDS ordering),
// transposed staging, 7-step-deep load pipeline, permlane half-combine.
//
// Lane (t = lane&31, h = lane>>5); D[q] = half-dot over p in [16h,16h+16):
//   D[q] = sum_p exp(w1*trans[t][p]) * exp(fv_{s'(q)}[p] - mref)
// Step s (jn = (s-1)&15):
//   Dn = sum_i trx[i]*ldsS[16h+i]  (MVM of last step's Sv; chain head)
//   part = sum_{l=1..15} D[(s-1-l)&15]*ew[l]  (off-chain) ; t==0 -> 0
//   part = fma(Dn, ew[0], part);  Sv = part + part^32 ; ldsS[t] = Sv
// Rescale once per 16 steps, folded into that block's first MVM.
// ---------------------------------------------------------------------------
__launch_bounds__(64, 1)
__global__ void semicrf_scan2_kernel(const float* __restrict__ efd,
                                     const float* __restrict__ trans,
                                     const float* __restrict__ tbound,
                                     const float* __restrict__ w1p,
                                     float* __restrict__ out, int S) {
    __shared__ float ldsS[TT];
    const int lane = threadIdx.x;
    const int t = lane & 31;
    const int h = lane >> 5;
    const float w1 = w1p[0];
    const char* ebase = (const char*)efd + (unsigned)t * 64u;

    float trx[16];
#pragma unroll
    for (int i = 0; i < 16; ++i)
        trx[i] = __expf(w1 * trans[t * TT + h * 16 + i]);

    float D[16];
#pragma unroll
    for (int k = 0; k < 16; ++k) D[k] = 0.0f;

    // ring: rv[st&7][q] = float4 of EFd[st][t][4q..4q+3]
    float4 rv[8][4];
#pragma unroll
    for (int st = 0; st < PD; ++st) {
        const char* p = ebase + (size_t)st * 2048;
        rv[st][0] = *(const float4*)(p);
        rv[st][1] = *(const float4*)(p + 16);
        rv[st][2] = *(const float4*)(p + 32);
        rv[st][3] = *(const float4*)(p + 48);
    }

    // sentence-start boundary emissions: bem[j] = exp(w2*feats[j][0][t]) = EFd[j][t][j]
    float etb0 = __expf(w1 * tbound[t]);
    float bem[16];
#pragma unroll
    for (int j = 0; j < 16; ++j)
        bem[j] = efd[(size_t)j * 512 + (size_t)t * 16 + j];

    float mref = 0.0f;
    float Svk = 1.0f;
    float inv = 1.0f;
    int s0 = 0;

#define SCRF_STEP(J, IS_B0, IS_FIRST, SCALED)                                 \
    {                                                                         \
        const int j_ = (J);                                                   \
        const int jn_ = (j_ - 1) & 15;                                        \
        /* this step's 16 emissions (read ring before any overwrite) */       \
        float ew_[16];                                                        \
        _Pragma("unroll")                                                     \
        for (int l = 0; l < 16; ++l) ew_[l] = rv[j_ & 7][l >> 2][l & 3];      \
        /* prefetch target s0+j_+PD into free slot (j_+PD)&7 */               \
        {                                                                     \
            int stq_ = s0 + j_ + PD;                                          \
            if (stq_ > S - 1) stq_ = S - 1;                                   \
            const char* pp_ = ebase + (size_t)stq_ * 2048;                    \
            rv[(j_ + PD) & 7][0] = *(const float4*)(pp_);                     \
            rv[(j_ + PD) & 7][1] = *(const float4*)(pp_ + 16);                \
            rv[(j_ + PD) & 7][2] = *(const float4*)(pp_ + 32);                \
            rv[(j_ + PD) & 7][3] = *(const float4*)(pp_ + 48);                \
        }                                                                     \
        /* MVM from LDS (Sv written last step) -> D[jn_]  (chain head) */     \
        float Dn_;                                                            \
        if (IS_FIRST) {                                                       \
            Dn_ = 0.0f;                                                       \
        } else {                                                              \
            const float4* lp_ = (const float4*)ldsS;                          \
            float4 a0_ = lp_[h * 4 + 0];                                      \
            float4 a1_ = lp_[h * 4 + 1];                                      \
            float4 a2_ = lp_[h * 4 + 2];                                      \
            float4 a3_ = lp_[h * 4 + 3];                                      \
            float d0_ = fmaf(trx[0], a0_.x, fmaf(trx[1], a0_.y,               \
                        fmaf(trx[2], a0_.z, trx[3] * a0_.w)));                \
            float d1_ = fmaf(trx[4], a1_.x, fmaf(trx[5], a1_.y,               \
                        fmaf(trx[6], a1_.z, trx[7] * a1_.w)));                \
            float d2_ = fmaf(trx[8], a2_.x, fmaf(trx[9], a2_.y,               \
                        fmaf(trx[10], a2_.z, trx[11] * a2_.w)));              \
            float d3_ = fmaf(trx[12], a3_.x, fmaf(trx[13], a3_.y,             \
                        fmaf(trx[14], a3_.z, trx[15] * a3_.w)));              \
            float dh_ = (d0_ + d1_) + (d2_ + d3_);                            \
            Dn_ = SCALED ? dh_ * inv : dh_;                                   \
            D[jn_] = Dn_;                                                     \
        }                                                                     \
        /* partial over l=1..15 (independent of Dn_, schedules in the gap) */ \
        float q0_ = 0.f, q1_ = 0.f, q2_ = 0.f, q3_ = 0.f;                     \
        _Pragma("unroll")                                                     \
        for (int l = 1; l <= 9; l += 4) {                                     \
            q0_ = fmaf(D[(j_ - 1 - l) & 15], ew_[l + 0], q0_);                \
            q1_ = fmaf(D[(j_ - 2 - l) & 15], ew_[l + 1], q1_);                \
            q2_ = fmaf(D[(j_ - 3 - l) & 15], ew_[l + 2], q2_);                \
            q3_ = fmaf(D[(j_ - 4 - l) & 15], ew_[l + 3], q3_);                \
        }                                                                     \
        q0_ = fmaf(D[(j_ - 14) & 15], ew_[13], q0_);                          \
        q1_ = fmaf(D[(j_ - 15) & 15], ew_[14], q1_);                          \
        q2_ = fmaf(D[(j_ - 16) & 15], ew_[15], q2_);                          \
        float p15_ = (q0_ + q1_) + (q2_ + q3_);                               \
        p15_ = (t == 0) ? 0.0f : p15_;     /* O-tag: span len 1 only */       \
        float part_ = fmaf(Dn_, ew_[0], p15_);                                \
        float Sv_ = swap_sum(part_);                                          \
        if (IS_B0) {                                                          \
            float bt_ = etb0 * bem[j_];                                       \
            if (j_ > 0) bt_ = (t == 0) ? 0.0f : bt_;                          \
            Sv_ += bt_;                                                       \
        }                                                                     \
        ldsS[t] = Sv_;                                                        \
        Svk = Sv_;                                                            \
    }

    // ---- block 0 (steps 0..15, boundary terms active, mref = 0) ----
    SCRF_STEP(0, true, true, false)
#pragma unroll
    for (int j = 1; j < 16; ++j) {
        SCRF_STEP(j, true, false, false)
    }

    // ---- main blocks ----
    const int nb = S / 16;
    for (int b = 1; b < nb; ++b) {
        s0 = 16 * b;
        // re-anchor: divide all rows by max_t(Sv_last), recenter to e^-20
        float mx = Svk;
#pragma unroll
        for (int m = 1; m <= 16; m <<= 1)
            mx = fmaxf(mx, __shfl_xor(mx, m));
        inv = 2.0611536e-09f / mx;          // e^-20 / mx
        mref += __logf(mx) + 20.0f;
#pragma unroll
        for (int k = 0; k < 16; ++k) D[k] *= inv;

        SCRF_STEP(0, false, false, true)    // MVM of pending LDS gets *inv
#pragma unroll
        for (int j = 1; j < 16; ++j) {
            SCRF_STEP(j, false, false, false)
        }
    }
#undef SCRF_STEP

    // ---- terminal: out = mref + log( sum_t Sv_last[t] * exp(w1*tb1[t]) )
    float etb1 = __expf(w1 * tbound[TT + t]);
    float val = Svk * etb1;
#pragma unroll
    for (int m = 1; m <= 16; m <<= 1) val += __shfl_xor(val, m);
    if (lane == 0) out[0] = mref + __logf(val);
}

// ---------------------------------------------------------------------------
// Fallback (ws too small): proven round-2 kernel, reads feats directly.
// ---------------------------------------------------------------------------
__launch_bounds__(64, 1)
__global__ void semicrf_scan_fb_kernel(const float* __restrict__ src,
                                       const float* __restrict__ trans,
                                       const float* __restrict__ tbound,
                                       const float* __restrict__ w1p,
                                       const float* __restrict__ w2p,
                                       float* __restrict__ out, int S) {
    __shared__ float4 ldsS4[8];
    const int lane = threadIdx.x;
    const int t = lane & 31;
    const int h = lane >> 5;
    const float w1 = w1p[0];
    const float w2 = w2p[0];
    const unsigned toff = (unsigned)t * 4u;
    const unsigned planeB = (unsigned)S * 128u;
    const size_t planeE = (size_t)S * TT;

    float trx[16];
#pragma unroll
    for (int i = 0; i < 16; ++i)
        trx[i] = __expf(w1 * trans[t * TT + h * 16 + i]);

    float D[16];
#pragma unroll
    for (int k = 0; k < 16; ++k) D[k] = 0.0f;

    unsigned off[16];
#pragma unroll
    for (int k = 0; k < 16; ++k) {
        int l = (-1 - k) & 15;
        int c = 0 - l; if (c < 0) c = 0;
        off[k] = (unsigned)(l * S + c) * 128u + toff;
    }

    float ring[4][16];
#pragma unroll
    for (int st = 0; st < 4; ++st) {
#pragma unroll
        for (int k = 0; k < 16; ++k)
            ring[st][k] = *(const float*)((const char*)src + off[k]);
        const int qr = st & 15;
        unsigned c = (unsigned)((st + 1 <= S - 1) ? st + 1 : S - 1);
#pragma unroll
        for (int k = 0; k < 16; ++k)
            off[k] = (k == qr) ? (c * 128u + toff) : (off[k] + planeB);
    }

    float etb0 = __expf(w1 * tbound[t]);
    float bem[16];
#pragma unroll
    for (int j = 0; j < 16; ++j)
        bem[j] = __expf(w2 * src[(size_t)j * planeE + (size_t)t]);

    float mref = 0.0f;
    float Svk = 1.0f;

#define FB_STEP(J, S0V, IS_B0)                                                \
    {                                                                         \
        const int j_ = (J);                                                   \
        float ewv[16];                                                        \
        _Pragma("unroll")                                                     \
        for (int k = 0; k < 16; ++k)                                          \
            ewv[k] = __expf(w2 * ring[j_ & 3][k]);                            \
        float p0 = 0.f, p1 = 0.f, p2 = 0.f, p3 = 0.f;                         \
        _Pragma("unroll")                                                     \
        for (int k = 0; k < 16; k += 4) {                                     \
            p0 = fmaf(D[k + 0], ewv[k + 0], p0);                              \
            p1 = fmaf(D[k + 1], ewv[k + 1], p1);                              \
            p2 = fmaf(D[k + 2], ewv[k + 2], p2);                              \
            p3 = fmaf(D[k + 3], ewv[k + 3], p3);                              \
        }                                                                     \
        float part = (p0 + p1) + (p2 + p3);                                   \
        {                                                                     \
            const int kp = (j_ - 1) & 15;                                     \
            float alt = D[kp] * ewv[kp];                                      \
            part = (t == 0) ? alt : part;                                     \
        }                                                                     \
        _Pragma("unroll")                                                     \
        for (int k = 0; k < 16; ++k)                                          \
            ring[(j_ + 4) & 3][k] =                                           \
                *(const float*)((const char*)src + off[k]);                   \
        {                                                                     \
            const int qr = (j_ + 4) & 15;                                     \
            long T1 = (long)(S0V) + j_ + 4 + 1;                               \
            unsigned c_ = (unsigned)(T1 <= (long)(S - 1) ? T1 : (long)(S - 1)); \
            _Pragma("unroll")                                                 \
            for (int k = 0; k < 16; ++k)                                      \
                off[k] = (k == qr) ? (c_ * 128u + toff) : (off[k] + planeB);  \
        }                                                                     \
        float Sv = part + __shfl_xor(part, 32);                               \
        if (IS_B0) {                                                          \
            float bt = etb0 * bem[j_];                                        \
            if (j_ > 0) bt = (t == 0) ? 0.0f : bt;                            \
            Sv += bt;                                                         \
        }                                                                     \
        ((float*)ldsS4)[t] = Sv;                                              \
        __syncthreads();                                                      \
        float4 a0 = ldsS4[h * 4 + 0];                                         \
        float4 a1 = ldsS4[h * 4 + 1];                                         \
        float4 a2 = ldsS4[h * 4 + 2];                                         \
        float4 a3 = ldsS4[h * 4 + 3];                                         \
        float dn0 = fmaf(trx[0],  a0.x, fmaf(trx[1],  a0.y,                   \
                    fmaf(trx[2],  a0.z, trx[3]  * a0.w)));                    \
        float dn1 = fmaf(trx[4],  a1.x, fmaf(trx[5],  a1.y,                   \
                    fmaf(trx[6],  a1.z, trx[7]  * a1.w)));                    \
        float dn2 = fmaf(trx[8],  a2.x, fmaf(trx[9],  a2.y,                   \
                    fmaf(trx[10], a2.z, trx[11] * a2.w)));                    \
        float dn3 = fmaf(trx[12], a3.x, fmaf(trx[13], a3.y,                   \
                    fmaf(trx[14], a3.z, trx[15] * a3.w)));                    \
        D[j_] = (dn0 + dn1) + (dn2 + dn3);                                    \
        Svk = Sv;                                                             \
    }

#pragma unroll
    for (int j = 0; j < 16; ++j) {
        FB_STEP(j, 0L, true)
    }
    const int nblocks = S / 16;
    long s0 = 16;
    for (int b = 1; b < nblocks; ++b) {
        float mx = Svk;
#pragma unroll
        for (int m = 1; m <= 16; m <<= 1)
            mx = fmaxf(mx, __shfl_xor(mx, m));
        float invv = 2.0611536e-09f / mx;
        mref += __logf(mx) + 20.0f;
#pragma unroll
        for (int k = 0; k < 16; ++k) D[k] *= invv;
#pragma unroll
        for (int j = 0; j < 16; ++j) {
            FB_STEP(j, s0, false)
        }
        s0 += 16;
    }
#undef FB_STEP

    float etb1 = __expf(w1 * tbound[TT + t]);
    float val = Svk * etb1;
#pragma unroll
    for (int m = 1; m <= 16; m <<= 1) val += __shfl_xor(val, m);
    if (lane == 0) out[0] = mref + __logf(val);
}

// ---------------------------------------------------------------------------
extern "C" void kernel_launch(void* const* d_in, const int* in_sizes, int n_in,
                              void* d_out, int out_size, void* d_ws, size_t ws_size,
                              hipStream_t stream) {
    const float* feats = (const float*)d_in[0];   // [L=16, S, T=32]
    const float* trans = (const float*)d_in[1];   // [T, T]
    const float* tb    = (const float*)d_in[2];   // [2, T]
    const float* w1    = (const float*)d_in[3];
    const float* w2    = (const float*)d_in[4];
    float* out = (float*)d_out;

    const int n = in_sizes[0];            // L*S*T
    const int S = n / (LL * TT);
    const size_t need = (size_t)n * sizeof(float);

    if (ws_size >= need) {
        float* efd = (float*)d_ws;
        efd_kernel<<<S, 512, 0, stream>>>(feats, w2, efd, S);
        semicrf_scan2_kernel<<<1, 64, 0, stream>>>(efd, trans, tb, w1, out, S);
    } else {
        semicrf_scan_fb_kernel<<<1, 64, 0, stream>>>(feats, trans, tb, w1, w2, out, S);
    }
}